// Round 3
// baseline (429.992 us; speedup 1.0000x reference)
//
#include <hip/hip_runtime.h>
#include <hip/hip_bf16.h>
#include <cstdint>
#include <cstddef>

typedef _Float16 half8 __attribute__((ext_vector_type(8)));
typedef float floatx16 __attribute__((ext_vector_type(16)));

#define DGRID 128
#define D3 (DGRID * DGRID * DGRID)

// lookup[lin(voxel)] = point index (pre-memset to -1 via 0xFF)
__global__ void scatter_lookup(const int* __restrict__ coords, int* __restrict__ lookup, int M) {
    int m = blockIdx.x * 256 + threadIdx.x;
    if (m >= M) return;
    int x = coords[3 * m], y = coords[3 * m + 1], z = coords[3 * m + 2];
    lookup[(x * DGRID + y) * DGRID + z] = m;
}

// nbr[k*M + m] = point index of neighbor at offset k (or -1). Shared by both layers.
__global__ void build_nbr(const int* __restrict__ coords, const int* __restrict__ lookup,
                          int* __restrict__ nbr, int M) {
    int m = blockIdx.x * 256 + threadIdx.x;
    if (m >= M) return;
    int x = coords[3 * m], y = coords[3 * m + 1], z = coords[3 * m + 2];
#pragma unroll
    for (int k = 0; k < 27; ++k) {
        int nx = x + k / 9 - 1, ny = y + (k / 3) % 3 - 1, nz = z + k % 3 - 1;
        int nidx = -1;
        if (((unsigned)nx < DGRID) && ((unsigned)ny < DGRID) && ((unsigned)nz < DGRID))
            nidx = lookup[(nx * DGRID + ny) * DGRID + nz];
        nbr[k * M + m] = nidx;
    }
}

// Whf in MFMA B-fragment order (see round 2; correctness-verified).
__global__ void convert_weights(const float* __restrict__ W1, const float* __restrict__ W2,
                                _Float16* __restrict__ Whf) {
    int idx = blockIdx.x * 256 + threadIdx.x;
    if (idx >= 2 * 27 * 4096) return;
    int j = idx & 7;
    int l = (idx >> 3) & 63;
    int f = (idx >> 9) & 7;
    int kL = idx >> 12;  // 0..53
    int k = kL % 27, L = kL / 27;
    int kk = f & 3, ct = f >> 2;
    int c = kk * 16 + (l >> 5) * 8 + j;
    int n = ct * 32 + (l & 31);
    const float* W = L ? W2 : W1;
    Whf[idx] = (_Float16)W[k * 4096 + c * 64 + n];
}

// Block = 128 threads = 2 waves on ONE 64-point tile, k-split: wave0 k=0..13,
// wave1 k=14..26 (+1 masked dummy). Partial 64x64 C tiles combined via one
// 16KB LDS exchange + single barrier; each wave epilogues half the rows.
// Pipeline: nbr depth AD+2, A depth AD (fp32:1, fp16:2), B depth 1. No other
// LDS, no per-k barriers.
template <typename SrcT, bool OUT_F16>
__global__ __launch_bounds__(128, 2) void spconv(const SrcT* __restrict__ x,
                                                 const _Float16* __restrict__ Whf,
                                                 const float* __restrict__ bias,
                                                 const int* __restrict__ nbr,
                                                 void* __restrict__ outp, int M) {
    constexpr int AD = (sizeof(SrcT) == 4) ? 1 : 2;  // A-prefetch depth
    constexpr int DN = AD + 2;                       // nbr-prefetch depth
    constexpr int NA = AD + 1;                       // A ring size
    const int t = threadIdx.x;
    const int lane = t & 63;
    const int wave = t >> 6;
    const int lrow = lane & 31;
    const int lhalf = lane >> 5;
    const int mw = blockIdx.x * 64;
    const int gm0 = mw + lrow;
    const int gm1 = mw + 32 + lrow;
    const bool in0 = gm0 < M, in1 = gm1 < M;

    const int kbase = wave ? 14 : 0;
    const int kEnd = wave ? 27 : 14;

    floatx16 acc[4];  // [rt*2+ct]
#pragma unroll
    for (int i = 0; i < 4; ++i)
#pragma unroll
        for (int j = 0; j < 16; ++j) acc[i][j] = 0.0f;

    const half8* wb = (const half8*)Whf + lane;

    auto kidx = [&](int i) { int k = kbase + i; return k < 27 ? k : 26; };

    auto loadB = [&](half8* dst, int k) {
#pragma unroll
        for (int f = 0; f < 8; ++f) dst[f] = wb[(k * 8 + f) * 64];
    };

    auto loadA = [&](half8* dst, int n0, int n1) {
#pragma unroll
        for (int rt = 0; rt < 2; ++rt) {
            int n = rt ? n1 : n0;
#pragma unroll
            for (int kk = 0; kk < 4; ++kk) {
                half8 z;
#pragma unroll
                for (int j = 0; j < 8; ++j) z[j] = (_Float16)0.f;
                dst[rt * 4 + kk] = z;
            }
            if (n >= 0) {
                if constexpr (sizeof(SrcT) == 4) {
                    const float4* p =
                        (const float4*)((const float*)x + (size_t)n * 64 + lhalf * 8);
#pragma unroll
                    for (int kk = 0; kk < 4; ++kk) {
                        float4 f0 = p[kk * 4], f1 = p[kk * 4 + 1];
                        half8 v;
                        v[0] = (_Float16)f0.x; v[1] = (_Float16)f0.y;
                        v[2] = (_Float16)f0.z; v[3] = (_Float16)f0.w;
                        v[4] = (_Float16)f1.x; v[5] = (_Float16)f1.y;
                        v[6] = (_Float16)f1.z; v[7] = (_Float16)f1.w;
                        dst[rt * 4 + kk] = v;
                    }
                } else {
                    const half8* p =
                        (const half8*)((const _Float16*)x + (size_t)n * 64 + lhalf * 8);
#pragma unroll
                    for (int kk = 0; kk < 4; ++kk) dst[rt * 4 + kk] = p[kk * 2];
                }
            }
        }
    };

    // nbr value ring: nv[j & 3] holds nidx(k_j)
    int nv0[4], nv1[4];
#pragma unroll
    for (int j = 0; j < 4; ++j) {
        bool v = (j < DN) && (kbase + j < kEnd);
        int kc = kidx(j);
        nv0[j] = (in0 && v) ? nbr[(size_t)kc * M + gm0] : -1;
        nv1[j] = (in1 && v) ? nbr[(size_t)kc * M + gm1] : -1;
    }

    half8 Ar[NA][8], Br[2][8];
    loadB(Br[0], kidx(0));
#pragma unroll
    for (int j = 0; j < AD; ++j) loadA(Ar[j], nv0[j & 3], nv1[j & 3]);

#pragma unroll
    for (int i = 0; i < 14; ++i) {
        // nbr prefetch (i+DN), 2-iter slack before its value feeds an A issue
        {
            int j = i + DN;
            if (j < 14) {
                bool v = kbase + j < kEnd;
                int kc = kidx(j);
                int slot = j & 3;
                nv0[slot] = (in0 && v) ? nbr[(size_t)kc * M + gm0] : -1;
                nv1[slot] = (in1 && v) ? nbr[(size_t)kc * M + gm1] : -1;
            }
        }
        // B prefetch (i+1): L2-hot, 1-iter slack
        if (i + 1 < 14) loadB(Br[(i + 1) & 1], kidx(i + 1));
        // A prefetch (i+AD)
        {
            int j = i + AD;
            if (j < 14) loadA(Ar[j % NA], nv0[j & 3], nv1[j & 3]);
        }
        // compute k_i
        half8* A = Ar[i % NA];
        half8* B = Br[i & 1];
#pragma unroll
        for (int rt = 0; rt < 2; ++rt)
#pragma unroll
            for (int ct = 0; ct < 2; ++ct)
#pragma unroll
                for (int kk = 0; kk < 4; ++kk)
                    acc[rt * 2 + ct] = __builtin_amdgcn_mfma_f32_32x32x16_f16(
                        A[rt * 4 + kk], B[ct * 4 + kk], acc[rt * 2 + ct], 0, 0, 0);
    }

    // ---- combine the two waves' partial C via LDS (one barrier) ----
    __shared__ __align__(16) float comb[2][32 * 64];  // [rt-half][row*64+col]
    const int ort = wave ? 0 : 1;  // rt half this wave gives away
    const int mrt = wave;          // rt half this wave keeps & stores
#pragma unroll
    for (int ct = 0; ct < 2; ++ct)
#pragma unroll
        for (int reg = 0; reg < 16; ++reg) {
            int row = (reg & 3) + 8 * (reg >> 2) + 4 * lhalf;  // 0..31 within tile
            comb[ort][row * 64 + ct * 32 + lrow] = acc[ort * 2 + ct][reg];
        }
    __syncthreads();

    const float bv0 = bias[lrow], bv1 = bias[32 + lrow];
#pragma unroll
    for (int ct = 0; ct < 2; ++ct) {
        const float bb = ct ? bv1 : bv0;
#pragma unroll
        for (int reg = 0; reg < 16; ++reg) {
            int row = (reg & 3) + 8 * (reg >> 2) + 4 * lhalf;
            int gm = mw + mrt * 32 + row;
            if (gm < M) {
                float v = acc[mrt * 2 + ct][reg] + comb[mrt][row * 64 + ct * 32 + lrow] + bb;
                v = v > 0.f ? v : 0.f;
                size_t off = (size_t)gm * 64 + ct * 32 + lrow;
                if constexpr (OUT_F16)
                    ((_Float16*)outp)[off] = (_Float16)v;
                else
                    ((float*)outp)[off] = v;
            }
        }
    }
}

extern "C" void kernel_launch(void* const* d_in, const int* in_sizes, int n_in,
                              void* d_out, int out_size, void* d_ws, size_t ws_size,
                              hipStream_t stream) {
    const float* feats = (const float*)d_in[0];
    const float* W1 = (const float*)d_in[1];
    const float* b1 = (const float*)d_in[2];
    const float* W2 = (const float*)d_in[3];
    const float* b2 = (const float*)d_in[4];
    const int* coords = (const int*)d_in[5];
    const int M = in_sizes[0] / 64;

    // workspace layout (same 32.4MB footprint that fit in rounds 1-2):
    int* lookup = (int*)d_ws;                          // D3 ints       = 8.4 MB
    int* nbr = lookup + (size_t)D3;                    // 27*M ints     = 10.8 MB
    _Float16* h = (_Float16*)(nbr + (size_t)27 * M);   // M*64 halves   = 12.8 MB
    _Float16* Whf = h + (size_t)M * 64;                // 2*27*4096 halves
    size_t need = (size_t)D3 * 4 + (size_t)27 * M * 4 + (size_t)M * 64 * 2 +
                  (size_t)2 * 27 * 4096 * 2;
    if (ws_size < need) return;

    hipMemsetAsync(lookup, 0xFF, (size_t)D3 * 4, stream);  // -1 everywhere
    int mb = (M + 255) / 256;
    scatter_lookup<<<mb, 256, 0, stream>>>(coords, lookup, M);
    convert_weights<<<(2 * 27 * 4096 + 255) / 256, 256, 0, stream>>>(W1, W2, Whf);
    build_nbr<<<mb, 256, 0, stream>>>(coords, lookup, nbr, M);

    int cb = (M + 63) / 64;
    spconv<float, true><<<cb, 128, 0, stream>>>(feats, Whf, b1, nbr, (void*)h, M);
    spconv<_Float16, false><<<cb, 128, 0, stream>>>(h, Whf + (size_t)27 * 4096, b2, nbr,
                                                    d_out, M);
}

// Round 4
// 217.204 us; speedup vs baseline: 1.9797x; 1.9797x over previous
//
#include <hip/hip_runtime.h>
#include <hip/hip_bf16.h>
#include <cstdint>
#include <cstddef>

typedef _Float16 half8 __attribute__((ext_vector_type(8)));
typedef float floatx16 __attribute__((ext_vector_type(16)));

#define DGRID 128
#define D3 (DGRID * DGRID * DGRID)
#define WSZ (2 * 27 * 4096)  // Whf halves

// ---------------- prep: scatter lookup + weight convert + zero rows ----------
// Whf in MFMA B-fragment order (round-2 verified): for layer L, offset k,
// frag f=ct*4+kk, lane l, j: Whf[((L*27+k)*8+f)*512 + l*8 + j]
//   = (fp16) W_L[k][ c=kk*16+(l>>5)*8+j ][ n=ct*32+(l&31) ]
__global__ void prep(const int* __restrict__ coords, const float* __restrict__ W1,
                     const float* __restrict__ W2, int* __restrict__ lookup,
                     _Float16* __restrict__ Whf, _Float16* __restrict__ h,
                     float* __restrict__ zrowf, int M) {
    int tid = blockIdx.x * 256 + threadIdx.x;
    if (tid < WSZ) {
        int idx = tid;
        int j = idx & 7;
        int l = (idx >> 3) & 63;
        int f = (idx >> 9) & 7;
        int kL = idx >> 12;  // 0..53
        int k = kL % 27, L = kL / 27;
        int kk = f & 3, ct = f >> 2;
        int c = kk * 16 + (l >> 5) * 8 + j;
        int n = ct * 32 + (l & 31);
        const float* W = L ? W2 : W1;
        Whf[idx] = (_Float16)W[k * 4096 + c * 64 + n];
    } else if (tid < WSZ + M) {
        int m = tid - WSZ;
        int x = coords[3 * m], y = coords[3 * m + 1], z = coords[3 * m + 2];
        lookup[(x * DGRID + y) * DGRID + z] = m;
    } else if (tid < WSZ + M + 64) {
        int j = tid - WSZ - M;
        h[(size_t)M * 64 + j] = (_Float16)0.f;  // zero row M of h (layer-2 input)
        zrowf[j] = 0.f;                          // fp32 zero row (layer-1 input)
    }
}

// nbr[k*M + m] = neighbor point index, CLAMPED: invalid -> M (zero row).
__global__ void build_nbr(const int* __restrict__ coords, const int* __restrict__ lookup,
                          int* __restrict__ nbr, int M) {
    int m = blockIdx.x * 256 + threadIdx.x;
    if (m >= M) return;
    int x = coords[3 * m], y = coords[3 * m + 1], z = coords[3 * m + 2];
#pragma unroll
    for (int k = 0; k < 27; ++k) {
        int nx = x + k / 9 - 1, ny = y + (k / 3) % 3 - 1, nz = z + k % 3 - 1;
        int nidx = -1;
        if (((unsigned)nx < DGRID) && ((unsigned)ny < DGRID) && ((unsigned)nz < DGRID))
            nidx = lookup[(nx * DGRID + ny) * DGRID + nz];
        nbr[k * M + m] = (nidx < 0) ? M : nidx;
    }
}

// One wave (64-thread block) computes a 32-point x 64-channel tile.
// Branch-free k-loop over 27 offsets, no LDS, no barriers.
// Pipeline: nbr depth AD+2, A depth AD (fp32:1, fp16:2), B depth 1.
template <typename SrcT, int AD, bool OUT_F16>
__global__ __launch_bounds__(64, 3) void spconv(const SrcT* __restrict__ x,
                                                const float* __restrict__ zrow,
                                                const _Float16* __restrict__ Whf,
                                                const float* __restrict__ bias,
                                                const int* __restrict__ nbr,
                                                void* __restrict__ outp, int M) {
    constexpr int NA = AD + 1;  // A ring size
    const int lane = threadIdx.x;
    const int lrow = lane & 31;
    const int lhalf = lane >> 5;
    const int mw = blockIdx.x * 32;
    const int gm = mw + lrow;
    const int gmc = gm < M ? gm : M - 1;  // clamped (tail safety)

    floatx16 acc[2];  // [ct] 32x32 C tiles
#pragma unroll
    for (int i = 0; i < 2; ++i)
#pragma unroll
        for (int j = 0; j < 16; ++j) acc[i][j] = 0.0f;

    const half8* wb = (const half8*)Whf + lane;

    auto loadB = [&](half8* dst, int k) {
#pragma unroll
        for (int f = 0; f < 8; ++f) dst[f] = wb[(k * 8 + f) * 64];
    };

    // A fragment: lane holds row m=lrow, k-elems kk*16 + lhalf*8 + j
    auto loadA = [&](half8* dst, int n) {
        if constexpr (sizeof(SrcT) == 4) {
            const float* rp = (n < M) ? ((const float*)x + (size_t)n * 64) : zrow;
            const float4* p = (const float4*)(rp + lhalf * 8);
#pragma unroll
            for (int kk = 0; kk < 4; ++kk) {
                float4 f0 = p[kk * 4], f1 = p[kk * 4 + 1];
                half8 v;
                v[0] = (_Float16)f0.x; v[1] = (_Float16)f0.y;
                v[2] = (_Float16)f0.z; v[3] = (_Float16)f0.w;
                v[4] = (_Float16)f1.x; v[5] = (_Float16)f1.y;
                v[6] = (_Float16)f1.z; v[7] = (_Float16)f1.w;
                dst[kk] = v;
            }
        } else {
            // row M is a zero row; no select needed
            const half8* p = (const half8*)((const _Float16*)x + (size_t)n * 64 + lhalf * 8);
#pragma unroll
            for (int kk = 0; kk < 4; ++kk) dst[kk] = p[kk * 2];
        }
    };

    // nbr value ring: nv[j & 3] = clamped nidx(k_j)
    int nv[4];
#pragma unroll
    for (int j = 0; j < 4; ++j) nv[j] = nbr[(size_t)j * M + gmc];

    half8 Ar[NA][4], Br[2][8];
    loadB(Br[0], 0);
#pragma unroll
    for (int j = 0; j < AD; ++j) loadA(Ar[j], nv[j & 3]);

#pragma unroll
    for (int i = 0; i < 27; ++i) {
        {   // nbr prefetch, 2-iter slack before it feeds an A issue
            int jn = i + AD + 2;
            if (jn < 27) nv[jn & 3] = nbr[(size_t)jn * M + gmc];
        }
        if (i + 1 < 27) loadB(Br[(i + 1) & 1], i + 1);  // B: L2-hot, 1-iter slack
        {   // A prefetch, AD-iter slack
            int ja = i + AD;
            if (ja < 27) loadA(Ar[ja % NA], nv[ja & 3]);
        }
        half8* A = Ar[i % NA];
        half8* B = Br[i & 1];
#pragma unroll
        for (int kk = 0; kk < 4; ++kk)
#pragma unroll
            for (int ct = 0; ct < 2; ++ct)
                acc[ct] = __builtin_amdgcn_mfma_f32_32x32x16_f16(A[kk], B[ct * 4 + kk],
                                                                 acc[ct], 0, 0, 0);
    }

    // epilogue: bias + relu; C/D: col=lane&31, row=(reg&3)+8*(reg>>2)+4*lhalf
    const float bv0 = bias[lrow], bv1 = bias[32 + lrow];
#pragma unroll
    for (int ct = 0; ct < 2; ++ct) {
        const float bb = ct ? bv1 : bv0;
#pragma unroll
        for (int reg = 0; reg < 16; ++reg) {
            int row = (reg & 3) + 8 * (reg >> 2) + 4 * lhalf;
            int g = mw + row;
            if (g < M) {
                float v = acc[ct][reg] + bb;
                v = v > 0.f ? v : 0.f;
                size_t off = (size_t)g * 64 + ct * 32 + lrow;
                if constexpr (OUT_F16)
                    ((_Float16*)outp)[off] = (_Float16)v;
                else
                    ((float*)outp)[off] = v;
            }
        }
    }
}

extern "C" void kernel_launch(void* const* d_in, const int* in_sizes, int n_in,
                              void* d_out, int out_size, void* d_ws, size_t ws_size,
                              hipStream_t stream) {
    const float* feats = (const float*)d_in[0];
    const float* W1 = (const float*)d_in[1];
    const float* b1 = (const float*)d_in[2];
    const float* W2 = (const float*)d_in[3];
    const float* b2 = (const float*)d_in[4];
    const int* coords = (const int*)d_in[5];
    const int M = in_sizes[0] / 64;

    // workspace layout (~32.5 MB, same scale that fit in rounds 1-3):
    int* lookup = (int*)d_ws;                            // D3 ints        = 8.4 MB
    int* nbr = lookup + (size_t)D3;                      // 27*M ints      = 10.8 MB
    _Float16* h = (_Float16*)(nbr + (size_t)27 * M);     // (M+1)*64 halves
    _Float16* Whf = h + (size_t)(M + 1) * 64;            // WSZ halves
    float* zrowf = (float*)(Whf + WSZ);                  // 64 floats
    size_t need = (size_t)D3 * 4 + (size_t)27 * M * 4 + (size_t)(M + 1) * 64 * 2 +
                  (size_t)WSZ * 2 + 64 * 4;
    if (ws_size < need) return;

    hipMemsetAsync(lookup, 0xFF, (size_t)D3 * 4, stream);  // -1 everywhere
    int pt = WSZ + M + 64;
    prep<<<(pt + 255) / 256, 256, 0, stream>>>(coords, W1, W2, lookup, Whf, h, zrowf, M);
    build_nbr<<<(M + 255) / 256, 256, 0, stream>>>(coords, lookup, nbr, M);

    int cb = (M + 31) / 32;
    spconv<float, 1, true><<<cb, 64, 0, stream>>>(feats, zrowf, Whf, b1, nbr, (void*)h, M);
    spconv<_Float16, 2, false><<<cb, 64, 0, stream>>>(h, zrowf, Whf + (size_t)27 * 4096,
                                                      b2, nbr, d_out, M);
}